// Round 11
// baseline (391.793 us; speedup 1.0000x reference)
//
#include <hip/hip_runtime.h>
#include <math.h>

#define BATCH 4
#define NQ 8192
#define KNB 8
#define K1 9             // top-9 incl self; self dropped in loss
#define NB 512           // x bins
#define XMIN -4.5f
#define BINW (9.0f / NB)
#define XSCALE (NB / 9.0f)
#define CAP 34           // >= 32 (one 2-burst pair) + margin
#define IDXMASK 8191u
#define KEYMASK 0xFFFFE000u
#define EPS_S 1e-3f

static __device__ __forceinline__ int binOf(float x) {
  return min(max((int)((x - XMIN) * XSCALE), 0), NB - 1);
}

#define CHAIN9(KEY) { unsigned kk = (KEY); \
  _Pragma("unroll") \
  for (int j = 0; j < K1; ++j) { \
    unsigned lo = min(kk, nk[j]); unsigned hi = max(kk, nk[j]); \
    nk[j] = lo; kk = hi; } }

// exact-chain one core burst of 16 sorted candidates (ungated)
#define CBURST(CB) { \
  const int ti = (bq + ((CB) << 4)) >> 2; \
  _Pragma("unroll") \
  for (int u4 = 0; u4 < 4; ++u4) { \
    const float4 X = x4[ti+u4], Y = y4[ti+u4], Z = z4[ti+u4]; \
    const uint4  I = i4[ti+u4]; \
    float dx,dy,dz,d; unsigned key; \
    dx=qx-X.x; dy=qy-Y.x; dz=qz-Z.x; d=dx*dx+dy*dy+dz*dz; \
    key=(__float_as_uint(d)&KEYMASK)|I.x; CHAIN9(key); \
    dx=qx-X.y; dy=qy-Y.y; dz=qz-Z.y; d=dx*dx+dy*dy+dz*dz; \
    key=(__float_as_uint(d)&KEYMASK)|I.y; CHAIN9(key); \
    dx=qx-X.z; dy=qy-Y.z; dz=qz-Z.z; d=dx*dx+dy*dy+dz*dz; \
    key=(__float_as_uint(d)&KEYMASK)|I.z; CHAIN9(key); \
    dx=qx-X.w; dy=qy-Y.w; dz=qz-Z.w; d=dx*dx+dy*dy+dz*dz; \
    key=(__float_as_uint(d)&KEYMASK)|I.w; CHAIN9(key); \
  } }

// drain survivors: recompute EXACT keys from sorted arrays, tighten gate
#define DRAINS() { \
  for (int ii = 0; ii < cnt; ++ii) { \
    int j = sbuf[base + ii]; \
    float dx = qx - sxs[bq + j], dy = qy - sys[bq + j], dz = qz - szs[bq + j]; \
    float d = dx*dx + dy*dy + dz*dz; \
    unsigned key = (__float_as_uint(d) & KEYMASK) | ssi[bq + j]; \
    if (key < nk[K1-1]) CHAIN9(key); \
  } \
  cnt = 0; \
  { float td = __uint_as_float(nk[K1-1] | 0x1FFFu); \
    thetaS = fminf(thetaS, 0.5f*(td - qq) + EPS_S); } }

#define GPROC(SS, JLOCAL) { \
  if ((SS) <= thetaS) { sbuf[base + cnt] = (unsigned short)(JLOCAL); cnt++; } }

#define SCORE4(S0,S1,S2,S3, X,Y,Z,H) \
  float S0 = fmaf(nqx, X.x, fmaf(nqy, Y.x, fmaf(nqz, Z.x, H.x))); \
  float S1 = fmaf(nqx, X.y, fmaf(nqy, Y.y, fmaf(nqz, Z.y, H.y))); \
  float S2 = fmaf(nqx, X.z, fmaf(nqy, Y.z, fmaf(nqz, Z.z, H.z))); \
  float S3 = fmaf(nqx, X.w, fmaf(nqy, Y.w, fmaf(nqz, Z.w, H.w)));

// gated score-burst of 16 sorted candidates
#define BURST(CB) { \
  const int jb = (CB) << 4; \
  const int ti = (bq + jb) >> 2; \
  const float4 X0=x4[ti],X1=x4[ti+1],X2=x4[ti+2],X3=x4[ti+3]; \
  const float4 Y0=y4[ti],Y1=y4[ti+1],Y2=y4[ti+2],Y3=y4[ti+3]; \
  const float4 Z0=z4[ti],Z1=z4[ti+1],Z2=z4[ti+2],Z3=z4[ti+3]; \
  const float4 H0=h4[ti],H1=h4[ti+1],H2=h4[ti+2],H3=h4[ti+3]; \
  SCORE4(s0,s1,s2,s3, X0,Y0,Z0,H0); \
  SCORE4(s4,s5,s6,s7, X1,Y1,Z1,H1); \
  SCORE4(s8,s9,sa,sb, X2,Y2,Z2,H2); \
  SCORE4(sc,sd,se,sf, X3,Y3,Z3,H3); \
  GPROC(s0,jb+0); GPROC(s1,jb+1); GPROC(s2,jb+2); GPROC(s3,jb+3); \
  GPROC(s4,jb+4); GPROC(s5,jb+5); GPROC(s6,jb+6); GPROC(s7,jb+7); \
  GPROC(s8,jb+8); GPROC(s9,jb+9); GPROC(sa,jb+10); GPROC(sb,jb+11); \
  GPROC(sc,jb+12); GPROC(sd,jb+13); GPROC(se,jb+14); GPROC(sf,jb+15); }

// ---- 1. fused counting sort by x-bin: hist -> scan -> scatter (1 block/batch) ----
__global__ __launch_bounds__(1024) void sort_kernel(
    const float* __restrict__ pc,
    float* __restrict__ sxs, float* __restrict__ sys, float* __restrict__ szs,
    float* __restrict__ shs, unsigned* __restrict__ ssi)
{
  __shared__ unsigned h[NB];
  __shared__ unsigned hs[NB];
  const int b = blockIdx.x;
  const int tid = threadIdx.x;
  const float* __restrict__ px = pc + (size_t)b * 3 * NQ;
  const float* __restrict__ py = px + NQ;
  const float* __restrict__ pz = px + 2 * NQ;
  if (tid < NB) h[tid] = 0u;
  __syncthreads();
#pragma unroll
  for (int k = 0; k < NQ / 1024; ++k) {
    const int n = tid + k * 1024;
    atomicAdd(&h[binOf(px[n])], 1u);
  }
  __syncthreads();
  if (tid < NB) hs[tid] = h[tid];
  __syncthreads();
  for (int off = 1; off < NB; off <<= 1) {
    unsigned v = (tid < NB && tid >= off) ? hs[tid - off] : 0u;
    __syncthreads();
    if (tid < NB) hs[tid] += v;
    __syncthreads();
  }
  if (tid < NB) h[tid] = hs[tid] - h[tid];   // exclusive start -> scatter cursor
  __syncthreads();
  const int bq = b * NQ;
#pragma unroll
  for (int k = 0; k < NQ / 1024; ++k) {
    const int n = tid + k * 1024;
    const float x = px[n], y = py[n], z = pz[n];
    const unsigned pos = atomicAdd(&h[binOf(x)], 1u);
    const int o = bq + (int)pos;
    sxs[o] = x; sys[o] = y; szs[o] = z;
    shs[o] = 0.5f * (x * x + y * y + z * z);
    ssi[o] = (unsigned)n;
  }
}

// ---- 2. fused sweep+loss: shared-window center-out scan, inline loss ----
__global__ __launch_bounds__(64) void sweep_loss_kernel(
    const float* __restrict__ pc, const float* __restrict__ pf,
    const float* __restrict__ sxs, const float* __restrict__ sys,
    const float* __restrict__ szs, const float* __restrict__ shs,
    const unsigned* __restrict__ ssi,
    float* __restrict__ acc, unsigned* __restrict__ doneCtr,
    float* __restrict__ out, int nBlocks)
{
  __shared__ unsigned short sbuf[64 * CAP];
  const int b = blockIdx.y;
  const int bq = b * NQ;
  const int W0 = blockIdx.x * 64;
  const int s = W0 + threadIdx.x;

  const float* __restrict__ px = pc + (size_t)b * 3 * NQ;
  const float* __restrict__ py = px + NQ;
  const float* __restrict__ pz = px + 2 * NQ;
  const float* __restrict__ fx = pf + (size_t)b * 3 * NQ;
  const float* __restrict__ fy = fx + NQ;
  const float* __restrict__ fz = fx + 2 * NQ;

  const float qx = sxs[bq + s], qy = sys[bq + s], qz = szs[bq + s];
  const unsigned selfO = ssi[bq + s];
  const float fqx = fx[selfO], fqy = fy[selfO], fqz = fz[selfO];
  const float nqx = -qx, nqy = -qy, nqz = -qz;
  const float qq = qx * qx + qy * qy + qz * qz;

  const float4* __restrict__ x4 = (const float4*)sxs;
  const float4* __restrict__ y4 = (const float4*)sys;
  const float4* __restrict__ z4 = (const float4*)szs;
  const float4* __restrict__ h4 = (const float4*)shs;
  const uint4*  __restrict__ i4 = (const uint4*)ssi;

  unsigned nk[K1];
#pragma unroll
  for (int j = 0; j < K1; ++j) nk[j] = 0xFFFFFFFFu;

  // core: chain the wave's own 64 sorted positions exactly (incl self, d=0)
  const int coreB = W0 >> 4;
  CBURST(coreB); CBURST(coreB + 1); CBURST(coreB + 2); CBURST(coreB + 3);

  // gate from core 9th (finite): d <= thD + 2*EPS superset
  float thetaS;
  { float td = __uint_as_float(nk[K1 - 1] | 0x1FFFu);
    thetaS = 0.5f * (td - qq) + EPS_S; }

  const unsigned base = (unsigned)threadIdx.x * CAP;
  int cnt = 0;
  const int CBMAX = NQ / 16 - 1;
  int cbR = coreB + 4, cbL = coreB - 1;
  bool goR = (cbR <= CBMAX), goL = (cbL >= 0);

  while (goR || goL) {
    if (goR) {
      BURST(cbR); ++cbR;
      if (cbR <= CBMAX) { BURST(cbR); ++cbR; }
      DRAINS();
      if (cbR > CBMAX) goR = false;
      else {
        // remaining-right x >= low edge of next position's (clamped) bin
        const float xe = sxs[bq + (cbR << 4)];
        const float dxe = (XMIN + binOf(xe) * BINW) - qx;
        const float thD = __uint_as_float(nk[K1 - 1] | 0x1FFFu);
        if (__all((dxe > 0.0f) && (dxe * dxe > thD))) goR = false;
      }
    }
    if (goL) {
      BURST(cbL); --cbL;
      if (cbL >= 0) { BURST(cbL); --cbL; }
      DRAINS();
      if (cbL < 0) goL = false;
      else {
        // remaining-left x <= high edge of last remaining position's bin
        const float xe = sxs[bq + (cbL << 4) + 15];
        const float dxe = qx - (XMIN + (binOf(xe) + 1) * BINW);
        const float thD = __uint_as_float(nk[K1 - 1] | 0x1FFFu);
        if (__all((dxe > 0.0f) && (dxe * dxe > thD))) goL = false;
      }
    }
  }
  DRAINS();

  // inline loss: drop self, exact distances from original arrays
  float ssum = 0.f, sdsum = 0.f;
#pragma unroll
  for (int j = 0; j < K1; ++j) {
    const int i = (int)(nk[j] & IDXMASK);
    if ((unsigned)i == selfO) continue;
    const float dx = qx - px[i], dy = qy - py[i], dz = qz - pz[i];
    const float d = dx * dx + dy * dy + dz * dz;
    const float e = expf(expf(-2.0f * d));      // exp(exp(-d/alpha)), alpha=0.5
    const float gx = fx[i] - fqx, gy = fy[i] - fqy, gz = fz[i] - fqz;
    const float diff = sqrtf(gx * gx + gy * gy + gz * gz);
    ssum += e; sdsum += e * diff;
  }

  for (int off = 32; off > 0; off >>= 1) {
    ssum += __shfl_down(ssum, off);
    sdsum += __shfl_down(sdsum, off);
  }
  if (threadIdx.x == 0) {
    atomicAdd(&acc[b * 2 + 0], ssum);
    atomicAdd(&acc[b * 2 + 1], sdsum);
    __threadfence();
    const unsigned done = atomicAdd(doneCtr, 1u);
    if (done == (unsigned)(nBlocks - 1)) {
      float sT = 0.f;
      for (int bb = 0; bb < BATCH; ++bb) {
        const float se = atomicAdd(&acc[bb * 2 + 0], 0.f);
        const float sd = atomicAdd(&acc[bb * 2 + 1], 0.f);
        sT += sd / se;
      }
      out[0] = sT * (1.0f / BATCH);
    }
  }
}

extern "C" void kernel_launch(void* const* d_in, const int* in_sizes, int n_in,
                              void* d_out, int out_size, void* d_ws, size_t ws_size,
                              hipStream_t stream) {
  const float* pc = (const float*)d_in[0];   // pc1:      (4,3,8192) f32
  const float* pf = (const float*)d_in[1];   // pred_flow:(4,3,8192) f32
  float* out = (float*)d_out;

  char* w = (char*)d_ws;
  float*    acc     = (float*)w;             // [0,32)
  unsigned* doneCtr = (unsigned*)(w + 64);   // [64,68)
  const size_t SA = 256;
  float*    sxs = (float*)(w + SA);
  float*    sys = (float*)(w + SA + 1 * 131072);
  float*    szs = (float*)(w + SA + 2 * 131072);
  float*    shs = (float*)(w + SA + 3 * 131072);
  unsigned* ssi = (unsigned*)(w + SA + 4 * 131072);

  hipMemsetAsync(d_ws, 0, 128, stream);      // acc + doneCtr

  sort_kernel<<<dim3(BATCH), 1024, 0, stream>>>(pc, sxs, sys, szs, shs, ssi);

  const int nBlocks = (NQ / 64) * BATCH;     // 512
  sweep_loss_kernel<<<dim3(NQ / 64, BATCH), 64, 0, stream>>>(
      pc, pf, sxs, sys, szs, shs, ssi, acc, doneCtr, out, nBlocks);
}

// Round 12
// 140.405 us; speedup vs baseline: 2.7904x; 2.7904x over previous
//
#include <hip/hip_runtime.h>
#include <math.h>

#define BATCH 4
#define NQ 8192
#define KNB 8
#define K1 9             // top-9 incl self; self dropped in loss
#define NB 512           // x bins
#define XMIN -4.5f
#define XSCALE (NB / 9.0f)
#define CAP 34           // u16 survivor slots per thread
#define THW 512          // theta staged window (sorted positions)
#define THS 128          // theta samples per part (SPART=2)
#define SPART 2
#define IDXMASK 8191u
#define KEYMASK 0xFFFFE000u
#define EPS_S 1e-3f

static __device__ __forceinline__ int binOf(float x) {
  return min(max((int)((x - XMIN) * XSCALE), 0), NB - 1);
}

#define CHAIN9(KEY) { unsigned kk = (KEY); \
  _Pragma("unroll") \
  for (int j = 0; j < K1; ++j) { \
    unsigned lo = min(kk, nk[j]); unsigned hi = max(kk, nk[j]); \
    nk[j] = lo; kk = hi; } }

#define CHAIN8(KEY) { unsigned kk = (KEY); \
  _Pragma("unroll") \
  for (int j = 0; j < KNB; ++j) { \
    unsigned lo = min(kk, nk[j]); unsigned hi = max(kk, nk[j]); \
    nk[j] = lo; kk = hi; } }

// drain survivors: recompute EXACT keys from sorted arrays, tighten gate
#define DRAINS() { \
  for (int ii = 0; ii < cnt; ++ii) { \
    int j = sbuf[base + ii]; \
    float dx = qx - sxs[bq + j], dy = qy - sys[bq + j], dz = qz - szs[bq + j]; \
    float d = dx*dx + dy*dy + dz*dz; \
    unsigned key = (__float_as_uint(d) & KEYMASK) | ssi[bq + j]; \
    if (key < nk[K1-1]) CHAIN9(key); \
  } \
  cnt = 0; \
  if (nk[K1-1] != 0xFFFFFFFFu) { \
    float td = __uint_as_float(nk[K1-1] | 0x1FFFu); \
    thetaS = fminf(thetaS, 0.5f*(td - qq) + EPS_S); \
  } }

#define GPROC(SS, JLOCAL) { \
  if ((SS) <= thetaS) { sbuf[base + cnt] = (unsigned short)(JLOCAL); cnt++; } }

#define SCORE4(S0,S1,S2,S3, X,Y,Z,H) \
  float S0 = fmaf(nqx, X.x, fmaf(nqy, Y.x, fmaf(nqz, Z.x, H.x))); \
  float S1 = fmaf(nqx, X.y, fmaf(nqy, Y.y, fmaf(nqz, Z.y, H.y))); \
  float S2 = fmaf(nqx, X.z, fmaf(nqy, Y.z, fmaf(nqz, Z.z, H.z))); \
  float S3 = fmaf(nqx, X.w, fmaf(nqy, Y.w, fmaf(nqz, Z.w, H.w)));

#define BURST(CB) { \
  const int jb = (CB) << 4; \
  const int ti = (bq + jb) >> 2; \
  const float4 X0=x4[ti],X1=x4[ti+1],X2=x4[ti+2],X3=x4[ti+3]; \
  const float4 Y0=y4[ti],Y1=y4[ti+1],Y2=y4[ti+2],Y3=y4[ti+3]; \
  const float4 Z0=z4[ti],Z1=z4[ti+1],Z2=z4[ti+2],Z3=z4[ti+3]; \
  const float4 H0=h4[ti],H1=h4[ti+1],H2=h4[ti+2],H3=h4[ti+3]; \
  SCORE4(s0,s1,s2,s3, X0,Y0,Z0,H0); \
  SCORE4(s4,s5,s6,s7, X1,Y1,Z1,H1); \
  SCORE4(s8,s9,sa,sb, X2,Y2,Z2,H2); \
  SCORE4(sc,sd,se,sf, X3,Y3,Z3,H3); \
  GPROC(s0,jb+0); GPROC(s1,jb+1); GPROC(s2,jb+2); GPROC(s3,jb+3); \
  GPROC(s4,jb+4); GPROC(s5,jb+5); GPROC(s6,jb+6); GPROC(s7,jb+7); \
  GPROC(s8,jb+8); GPROC(s9,jb+9); GPROC(sa,jb+10); GPROC(sb,jb+11); \
  GPROC(sc,jb+12); GPROC(sd,jb+13); GPROC(se,jb+14); GPROC(sf,jb+15); }

// ---- 1. fused counting sort by x-bin (1 block per batch) + binStart ----
__global__ __launch_bounds__(1024) void sort_kernel(
    const float* __restrict__ pc,
    float* __restrict__ sxs, float* __restrict__ sys, float* __restrict__ szs,
    float* __restrict__ shs, unsigned* __restrict__ ssi,
    unsigned* __restrict__ binStart)
{
  __shared__ unsigned h[NB];
  __shared__ unsigned hs[NB];
  const int b = blockIdx.x;
  const int tid = threadIdx.x;
  const float* __restrict__ px = pc + (size_t)b * 3 * NQ;
  const float* __restrict__ py = px + NQ;
  const float* __restrict__ pz = px + 2 * NQ;
  if (tid < NB) h[tid] = 0u;
  __syncthreads();
#pragma unroll
  for (int k = 0; k < NQ / 1024; ++k) {
    const int n = tid + k * 1024;
    atomicAdd(&h[binOf(px[n])], 1u);
  }
  __syncthreads();
  if (tid < NB) hs[tid] = h[tid];
  __syncthreads();
  for (int off = 1; off < NB; off <<= 1) {
    unsigned v = (tid < NB && tid >= off) ? hs[tid - off] : 0u;
    __syncthreads();
    if (tid < NB) hs[tid] += v;
    __syncthreads();
  }
  if (tid < NB) {
    const unsigned excl = hs[tid] - h[tid];
    binStart[b * (NB + 1) + tid] = excl;
    h[tid] = excl;                           // scatter cursor
  }
  if (tid == 0) binStart[b * (NB + 1) + NB] = NQ;
  __syncthreads();
  const int bq = b * NQ;
#pragma unroll
  for (int k = 0; k < NQ / 1024; ++k) {
    const int n = tid + k * 1024;
    const float x = px[n], y = py[n], z = pz[n];
    const unsigned pos = atomicAdd(&h[binOf(x)], 1u);
    const int o = bq + (int)pos;
    sxs[o] = x; sys[o] = y; szs[o] = z;
    shs[o] = 0.5f * (x * x + y * y + z * z);
    ssi[o] = (unsigned)n;
  }
}

// ---- 2. theta: 9th of 128 x-LOCAL sorted samples (x2 parts, min-merged) ----
__global__ __launch_bounds__(256) void theta_kernel(
    const float* __restrict__ sxs, const float* __restrict__ sys,
    const float* __restrict__ szs, unsigned* __restrict__ thetaOut)
{
  __shared__ float swx[THW], swy[THW], swz[THW];
  const int b = blockIdx.y, p = blockIdx.z;
  const int B0 = blockIdx.x * 256;
  const int bq = b * NQ;
  const int stg0 = min(max(B0 - 128, 0), NQ - THW);
#pragma unroll
  for (int k = 0; k < THW / 256; ++k) {
    const int i = threadIdx.x + k * 256;
    swx[i] = sxs[bq + stg0 + i];
    swy[i] = sys[bq + stg0 + i];
    swz[i] = szs[bq + stg0 + i];
  }
  __syncthreads();
  const int s = B0 + threadIdx.x;
  const float qx = swx[s - stg0], qy = swy[s - stg0], qz = swz[s - stg0];
  const int w = min(max(s - 128, stg0), stg0 + THW - 256) - stg0;  // [0,256]
  unsigned nk[K1];
#pragma unroll
  for (int j = 0; j < K1; ++j) nk[j] = 0xFFFFFFFFu;
  for (int k = 0; k < THS; ++k) {
    const int i = w + 2 * k + p;
    const float dx = qx - swx[i], dy = qy - swy[i], dz = qz - swz[i];
    const float d = dx * dx + dy * dy + dz * dz;
    CHAIN9(__float_as_uint(d));
  }
  thetaOut[(size_t)(bq + s) * SPART + p] = nk[K1 - 1] | 0x1FFFu;
}

// ---- 3. windowed gated scan (R9 body, contiguous per-part sub-range) ----
__global__ __launch_bounds__(256) void knn_kernel(
    const float* __restrict__ sxs, const float* __restrict__ sys,
    const float* __restrict__ szs, const float* __restrict__ shs,
    const unsigned* __restrict__ ssi, const unsigned* __restrict__ binStart,
    const unsigned* __restrict__ thetaIn, unsigned* __restrict__ wsK, int P)
{
  __shared__ unsigned short sbuf[256 * CAP];
  const int b = blockIdx.y, p = blockIdx.z;
  const int s = blockIdx.x * 256 + threadIdx.x;
  const int bq = b * NQ;
  const float qx = sxs[bq + s], qy = sys[bq + s], qz = szs[bq + s];
  const float nqx = -qx, nqy = -qy, nqz = -qz;
  const float qq = qx * qx + qy * qy + qz * qz;

  const uint2 th = ((const uint2*)thetaIn)[bq + s];
  const float thetaD = __uint_as_float(min(th.x, th.y));
  float thetaS = 0.5f * (thetaD - qq) + EPS_S;
  const float r = sqrtf(thetaD) * 1.0001f + 1e-7f;
  unsigned LO = binStart[b * (NB + 1) + binOf(qx - r)];
  unsigned HI = binStart[b * (NB + 1) + binOf(qx + r) + 1];
  for (int off = 32; off; off >>= 1) {
    LO = min(LO, (unsigned)__shfl_xor((int)LO, off));
    HI = max(HI, (unsigned)__shfl_xor((int)HI, off));
  }
  const int b0 = __builtin_amdgcn_readfirstlane((int)LO) >> 4;
  const int b1 = (__builtin_amdgcn_readfirstlane((int)HI) + 15) >> 4;  // excl
  const int nb = b1 - b0;
  const int st = b0 + (p * nb) / P;
  const int en = b0 + ((p + 1) * nb) / P;

  unsigned nk[K1];
#pragma unroll
  for (int j = 0; j < K1; ++j) nk[j] = 0xFFFFFFFFu;
  const unsigned base = (unsigned)threadIdx.x * CAP;
  int cnt = 0;
  const float4* __restrict__ x4 = (const float4*)sxs;
  const float4* __restrict__ y4 = (const float4*)sys;
  const float4* __restrict__ z4 = (const float4*)szs;
  const float4* __restrict__ h4 = (const float4*)shs;

  for (int cb = st; cb < en; ++cb) {
    if (__any(cnt >= CAP - 16)) { DRAINS(); }
    BURST(cb);
  }
  DRAINS();

#pragma unroll
  for (int j = 0; j < K1; ++j)
    wsK[((size_t)(b * P + p) * K1 + j) * NQ + s] = nk[j];
}

// ---- 4. loss + final fused (R10-proven) ----
__global__ __launch_bounds__(64) void loss_kernel(
    const float* __restrict__ pc, const float* __restrict__ pf,
    const float* __restrict__ sxs, const float* __restrict__ sys,
    const float* __restrict__ szs, const unsigned* __restrict__ ssi,
    const unsigned* __restrict__ wsK, float* __restrict__ acc,
    unsigned* __restrict__ doneCtr, float* __restrict__ out,
    int P, int nBlocks)
{
  const int b = blockIdx.y;
  const int s = blockIdx.x * 64 + threadIdx.x;
  const int bq = b * NQ;
  const float* __restrict__ px = pc + (size_t)b * 3 * NQ;
  const float* __restrict__ py = px + NQ;
  const float* __restrict__ pz = px + 2 * NQ;
  const float* __restrict__ fx = pf + (size_t)b * 3 * NQ;
  const float* __restrict__ fy = fx + NQ;
  const float* __restrict__ fz = fx + 2 * NQ;

  const unsigned qorig = ssi[bq + s];
  unsigned nk[KNB];
#pragma unroll
  for (int j = 0; j < KNB; ++j) nk[j] = 0xFFFFFFFFu;

  const int total = P * K1;
  const size_t stride0 = (size_t)b * P * K1;
  for (int m0 = 0; m0 < total; m0 += K1) {
    unsigned kb[K1];
#pragma unroll
    for (int u = 0; u < K1; ++u)
      kb[u] = wsK[(stride0 + m0 + u) * NQ + s];
#pragma unroll
    for (int u = 0; u < K1; ++u) {
      unsigned key = kb[u];
      if ((key & IDXMASK) == qorig) continue;   // drop self
      if (key < nk[KNB - 1]) CHAIN8(key);
    }
  }

  const float qx = sxs[bq + s], qy = sys[bq + s], qz = szs[bq + s];
  const float fqx = fx[qorig], fqy = fy[qorig], fqz = fz[qorig];
  float ssum = 0.f, sdsum = 0.f;
#pragma unroll
  for (int j = 0; j < KNB; ++j) {
    const int i = (int)(nk[j] & IDXMASK);
    const float dx = qx - px[i], dy = qy - py[i], dz = qz - pz[i];
    const float d = dx * dx + dy * dy + dz * dz;
    const float e = expf(expf(-2.0f * d));      // exp(exp(-d/alpha)), alpha=0.5
    const float gx = fx[i] - fqx, gy = fy[i] - fqy, gz = fz[i] - fqz;
    const float diff = sqrtf(gx * gx + gy * gy + gz * gz);
    ssum += e; sdsum += e * diff;
  }

  for (int off = 32; off > 0; off >>= 1) {
    ssum += __shfl_down(ssum, off);
    sdsum += __shfl_down(sdsum, off);
  }
  if (threadIdx.x == 0) {
    atomicAdd(&acc[b * 2 + 0], ssum);
    atomicAdd(&acc[b * 2 + 1], sdsum);
    __threadfence();
    const unsigned done = atomicAdd(doneCtr, 1u);
    if (done == (unsigned)(nBlocks - 1)) {
      float sT = 0.f;
      for (int bb = 0; bb < BATCH; ++bb) {
        const float se = atomicAdd(&acc[bb * 2 + 0], 0.f);
        const float sd = atomicAdd(&acc[bb * 2 + 1], 0.f);
        sT += sd / se;
      }
      out[0] = sT * (1.0f / BATCH);
    }
  }
}

extern "C" void kernel_launch(void* const* d_in, const int* in_sizes, int n_in,
                              void* d_out, int out_size, void* d_ws, size_t ws_size,
                              hipStream_t stream) {
  const float* pc = (const float*)d_in[0];   // pc1:      (4,3,8192) f32
  const float* pf = (const float*)d_in[1];   // pred_flow:(4,3,8192) f32
  float* out = (float*)d_out;

  char* w = (char*)d_ws;
  float*    acc      = (float*)w;                  // [0,32)
  unsigned* doneCtr  = (unsigned*)(w + 64);        // [64,68)
  unsigned* binStart = (unsigned*)(w + 256);       // 4*513*4 = 8208 -> ends 8464
  const size_t SA = 16384;                         // 16B aligned
  float*    sxs = (float*)(w + SA);
  float*    sys = (float*)(w + SA + 1 * 131072);
  float*    szs = (float*)(w + SA + 2 * 131072);
  float*    shs = (float*)(w + SA + 3 * 131072);
  unsigned* ssi = (unsigned*)(w + SA + 4 * 131072);
  const size_t TH = SA + 5 * 131072;
  unsigned* thetaBuf = (unsigned*)(w + TH);        // 4*8192*2*4 = 256 KB
  const size_t WK = TH + (size_t)BATCH * NQ * SPART * 4;
  unsigned* wsK = (unsigned*)(w + WK);

  const size_t needP16 = WK + (size_t)BATCH * NQ * 16 * K1 * 4;
  const size_t needP8  = WK + (size_t)BATCH * NQ * 8  * K1 * 4;
  const size_t needP4  = WK + (size_t)BATCH * NQ * 4  * K1 * 4;
  const int P = (ws_size >= needP16) ? 16 : (ws_size >= needP8) ? 8
              : (ws_size >= needP4) ? 4 : 2;

  hipMemsetAsync(d_ws, 0, 128, stream);            // acc + doneCtr

  sort_kernel<<<dim3(BATCH), 1024, 0, stream>>>(pc, sxs, sys, szs, shs, ssi,
                                                binStart);
  theta_kernel<<<dim3(NQ / 256, BATCH, SPART), 256, 0, stream>>>(
      sxs, sys, szs, thetaBuf);
  knn_kernel<<<dim3(NQ / 256, BATCH, P), 256, 0, stream>>>(
      sxs, sys, szs, shs, ssi, binStart, thetaBuf, wsK, P);
  const int nBlocks = (NQ / 64) * BATCH;
  loss_kernel<<<dim3(NQ / 64, BATCH), 64, 0, stream>>>(
      pc, pf, sxs, sys, szs, ssi, wsK, acc, doneCtr, out, P, nBlocks);
}